// Round 17
// baseline (430.979 us; speedup 1.0000x reference)
//
#include <hip/hip_runtime.h>
#include <stdint.h>

#define M_DIM 8192
#define N_DIM 4096
#define K_DIM 4096
#define CBN   (K_DIM/8)   // 512 column groups per row

typedef __attribute__((ext_vector_type(4)))  int   i32x4;
typedef __attribute__((ext_vector_type(16))) char  i8x16;

#define AS_GLOBAL(p) (const __attribute__((address_space(1))) void*)(p)
#define AS_LDS(p)    (__attribute__((address_space(3))) void*)(p)

// ---------------------------------------------------------------------------
// Kernel 1: per (ob, cb) pick top-4 columns (of 8) by L1 mass over 64 rows.
// ---------------------------------------------------------------------------
__global__ __launch_bounds__(256) void venom_sel(const float* __restrict__ W,
                                                 uint16_t* __restrict__ sel) {
    int t   = threadIdx.x;
    int ob  = blockIdx.x;
    int col = blockIdx.y * 256 + t;
    const float* p = W + (size_t)(ob * 64) * K_DIM + col;
    double s = 0.0;
    #pragma unroll 16
    for (int r = 0; r < 64; ++r) s += fabsf(p[(size_t)r * K_DIM]);

    int lane = t & 63;
    int base = lane & ~7;
    double sc[8];
    #pragma unroll
    for (int j = 0; j < 8; ++j) sc[j] = __shfl(s, base + j, 64);

    uint32_t packed = 0;
    #pragma unroll
    for (int c = 0; c < 8; ++c) {
        int rank = 0;
        #pragma unroll
        for (int j = 0; j < 8; ++j)
            rank += (sc[j] > sc[c]) || (sc[j] == sc[c] && j < c);
        if (rank < 4) packed |= (uint32_t)c << (4 * rank);
    }
    if ((lane & 7) == 0) {
        int cb = col >> 3;
        sel[ob * CBN + cb] = (uint16_t)packed;
    }
}

// ---------------------------------------------------------------------------
// Kernel 2: masked weight -> int8 with per-output-row symmetric scale.
// ---------------------------------------------------------------------------
__global__ __launch_bounds__(256) void venom_packq(const float* __restrict__ W,
                                                   const uint16_t* __restrict__ sel,
                                                   int8_t* __restrict__ Wq,
                                                   float* __restrict__ sw) {
    __shared__ float red[4];
    int o = blockIdx.x;
    const float* rowp = W + (size_t)o * K_DIM;
    float mv[16];
    float m = 0.0f;
    #pragma unroll
    for (int h = 0; h < 2; ++h) {
        int cb = threadIdx.x * 2 + h;
        uint32_t pk = sel[(o >> 6) * CBN + cb];
        const float* p = rowp + cb * 8;
        float4 a = *(const float4*)p;
        float4 b = *(const float4*)(p + 4);
        float w[8] = {a.x, a.y, a.z, a.w, b.x, b.y, b.z, b.w};
        int   c[4]; float v[4];
        #pragma unroll
        for (int pz = 0; pz < 4; ++pz) {
            c[pz] = (pk >> (4 * pz)) & 7;
            v[pz] = fabsf(w[c[pz]]);
        }
        uint32_t keep = 0;
        #pragma unroll
        for (int pz = 0; pz < 4; ++pz) {
            int cnt = 0;
            #pragma unroll
            for (int q = 0; q < 4; ++q)
                cnt += (v[q] > v[pz]) || (v[q] == v[pz] && q < pz);
            if (cnt < 2) keep |= 1u << c[pz];
        }
        #pragma unroll
        for (int j = 0; j < 8; ++j) {
            float x = ((keep >> j) & 1) ? w[j] : 0.0f;
            mv[h * 8 + j] = x;
            m = fmaxf(m, fabsf(x));
        }
    }
    #pragma unroll
    for (int off = 32; off >= 1; off >>= 1) m = fmaxf(m, __shfl_xor(m, off, 64));
    int lane = threadIdx.x & 63, wid = threadIdx.x >> 6;
    if (lane == 0) red[wid] = m;
    __syncthreads();
    m = fmaxf(fmaxf(red[0], red[1]), fmaxf(red[2], red[3]));
    float inv = m > 0.0f ? 127.0f / m : 0.0f;

    i8x16 q;
    #pragma unroll
    for (int j = 0; j < 16; ++j) {
        float qq = rintf(mv[j] * inv);
        qq = fminf(127.0f, fmaxf(-127.0f, qq));
        q[j] = (char)(int)qq;
    }
    *(i8x16*)(Wq + (size_t)o * K_DIM + threadIdx.x * 16) = q;
    if (threadIdx.x == 0) sw[o] = m > 0.0f ? m / 127.0f : 1.0f;
}

// ---------------------------------------------------------------------------
// Kernel 3: x f32 -> int8 with per-row symmetric scale. One block per row.
// ---------------------------------------------------------------------------
__global__ __launch_bounds__(256) void xq_kernel(const float* __restrict__ X,
                                                 int8_t* __restrict__ Xq,
                                                 float* __restrict__ sx) {
    __shared__ float red[4];
    int row = blockIdx.x;
    const float4* p = (const float4*)(X + (size_t)row * K_DIM) + threadIdx.x * 4;
    float4 v0 = p[0], v1 = p[1], v2 = p[2], v3 = p[3];
    float vv[16] = {v0.x, v0.y, v0.z, v0.w, v1.x, v1.y, v1.z, v1.w,
                    v2.x, v2.y, v2.z, v2.w, v3.x, v3.y, v3.z, v3.w};
    float m = 0.0f;
    #pragma unroll
    for (int j = 0; j < 16; ++j) m = fmaxf(m, fabsf(vv[j]));
    #pragma unroll
    for (int off = 32; off >= 1; off >>= 1) m = fmaxf(m, __shfl_xor(m, off, 64));
    int lane = threadIdx.x & 63, wid = threadIdx.x >> 6;
    if (lane == 0) red[wid] = m;
    __syncthreads();
    m = fmaxf(fmaxf(red[0], red[1]), fmaxf(red[2], red[3]));
    float inv = m > 0.0f ? 127.0f / m : 0.0f;

    i8x16 q;
    #pragma unroll
    for (int j = 0; j < 16; ++j) {
        float qq = rintf(vv[j] * inv);
        qq = fminf(127.0f, fmaxf(-127.0f, qq));
        q[j] = (char)(int)qq;
    }
    *(i8x16*)(Xq + (size_t)row * K_DIM + threadIdx.x * 16) = q;
    if (threadIdx.x == 0) sx[row] = m > 0.0f ? m / 127.0f : 1.0f;
}

// ---------------------------------------------------------------------------
// Kernel 4: 256x256 int8 GEMM, A DIRECT-TO-REGISTER (LDS holds B only).
// Rationale: 9 schedule variants all measured wall = LDS(1152cy)+MFMA(1306cy)
// per slice — lgkm service never overlaps MFMA. A-frags need no cross-lane
// shuffle -> load them global->VGPR (vmem pipe, which DOES hide under MFMA —
// every round's staging proved it). LDS reads drop 12->4/wave/slice (B only,
// shared by both wm halves): LDS window 1152->385cy. A is register-double-
// buffered (afA/afB static names, rule #20); loads for slice s+1 issue under
// slice s's MFMA (~1300cy cover); compiler emits the exact counted vmcnt for
// A-use (its wait vmcnt(10) also drains Bst(s+1) — explicit CKPT(10) kept as
// declared ledger).
// B ledger (round-13-proven, 4 regions x 16KB, stage-lead 2):
//   SP s: { 4 ds_read B (region s&3) | stage B(s+2) (2 gload_lds) |
//           load A(s+1) (8 dwordx4 -> afNext) | lgkm(0) | 32 MFMA (afCur) |
//           CKPT vmcnt(10) | BAR }
//   queue at CKPT@s: [Bst(s+1)@s-1 (2), A(s)@s-1 (8) — both drained by
//   MFMA's A-wait], Bst(s+2)@s (2), A(s+1)@s (8) -> vmcnt(10) leaves those.
//   W-after-R: stage@s overwrites region s-2, read @s-2, lgkm(0)-drained
//   2 barriers earlier. Tail: s=62 no stage -> CKPT(8) (drains Bst63);
//   s=63 no stage/load/CKPT. Prologue: stage B0,B1; load A0->afA;
//   vmcnt(10) drains Bst0; BAR.
// Frags 16x16x64 i8; B XOR 16B-chunk swizzle (0 conflicts); XCD swizzle.
// Epilogue: C = sx[row]*sw[col]*acc + bias.
// ---------------------------------------------------------------------------
__global__ __launch_bounds__(512, 2) void gemm256_i8(const int8_t* __restrict__ A,
                                                     const int8_t* __restrict__ B,
                                                     const float* __restrict__ sx,
                                                     const float* __restrict__ sw,
                                                     const float* __restrict__ bias,
                                                     float* __restrict__ C) {
    __shared__ __align__(16) unsigned char smem[65536]; // B only: 4 x 16KB

    int t    = threadIdx.x;
    int wid  = t >> 6;
    int lane = t & 63;
    int l16  = lane & 15;
    int lk   = lane >> 4;
    int wm   = wid >> 2;     // wave row-half (128 rows)
    int wn   = wid & 3;      // wave col-quarter (64 cols)

    // XCD-aware bijective swizzle (512 blocks % 8 == 0)
    int bid = blockIdx.x;
    int swz = (bid & 7) * ((int)gridDim.x >> 3) + (bid >> 3);
    int bm  = swz >> 4;
    int bn  = swz & 15;

    // B staging: thread t covers row r=t>>2 (and r+128); stored 16B chunk t&3
    // holds logical chunk (t&3)^((r>>1)&3) = (t&3)^((t>>3)&3)
    int gch = ((t & 3) ^ ((t >> 3) & 3)) * 16;
    const int8_t* bgbase = B + (size_t)(bn * 256 + (t >> 2)) * K_DIM + gch;

    auto stageB2 = [&](int slice) {
        const int8_t* gb = bgbase + slice * 64;
        char* lb = (char*)smem + (slice & 3) * 16384 + wid * 1024;
        __builtin_amdgcn_global_load_lds(AS_GLOBAL(gb), AS_LDS(lb), 16, 0, 0);
        __builtin_amdgcn_global_load_lds(AS_GLOBAL(gb + (size_t)128 * K_DIM), AS_LDS(lb + 8192), 16, 0, 0);
    };

    // B read-side: row R = wn*64+g*16+l16, chunk lk -> phys lk^((l16>>1)&3)
    int koff = ((lk ^ ((l16 >> 1) & 3)) << 4);
    const char* brdb = (const char*)smem + (wn * 64 + l16) * 64 + koff;

    // A direct: lane reads 16B of row bm*256+wm*128+i*16+l16 at chunk lk
    const int8_t* ap = A + (size_t)(bm * 256 + wm * 128 + l16) * K_DIM + lk * 16;

    i32x4 acc[8][4] = {};
    i32x4 afA[8], afB[8], bfr[4];

#define LGKM0() { asm volatile("s_waitcnt lgkmcnt(0)" ::: "memory");                 \
                  __builtin_amdgcn_sched_barrier(0); }
#define CKPTN(N) { asm volatile("s_waitcnt vmcnt(" #N ")" ::: "memory");             \
                   __builtin_amdgcn_sched_barrier(0); }
#define BAR()   { __builtin_amdgcn_s_barrier(); __builtin_amdgcn_sched_barrier(0); }

#define LOAD_A(DST, P)                                                               \
    { _Pragma("unroll")                                                              \
      for (int i = 0; i < 8; ++i)                                                    \
          DST[i] = *(const i32x4*)((P) + (size_t)i * 16 * K_DIM); }

    // SP: RN = region (s&3); AFC = current A frags; AFN = next A frags;
    // SS = slice staged (s+2); DOSTAGE; DOLOADA; CK: 10 / 8 / -1 (none).
#define SP(RN, AFC, AFN, SS, DOSTAGE, DOLOADA, CK)                                   \
    {                                                                                \
        const char* bbase = brdb + (RN) * 16384;                                     \
        _Pragma("unroll")                                                            \
        for (int g = 0; g < 4; ++g) bfr[g] = *(const i32x4*)(bbase + g * 1024);      \
        if (DOSTAGE) stageB2(SS);                                                    \
        if (DOLOADA) { LOAD_A(AFN, apn) apn += 64; }                                 \
        LGKM0()                                                                      \
        __builtin_amdgcn_s_setprio(1);                                               \
        _Pragma("unroll")                                                            \
        for (int i = 0; i < 8; ++i)                                                  \
            _Pragma("unroll")                                                        \
            for (int g = 0; g < 4; ++g)                                              \
                acc[i][g] = __builtin_amdgcn_mfma_i32_16x16x64_i8(AFC[i], bfr[g], acc[i][g], 0, 0, 0); \
        __builtin_amdgcn_s_setprio(0);                                               \
        __builtin_amdgcn_sched_barrier(0);                                           \
        if ((CK) == 10) { CKPTN(10) } else if ((CK) == 8) { CKPTN(8) }               \
        BAR()                                                                        \
    }

    // prologue: stage B slices 0,1; load A slice 0 -> afA; drain Bst0; sync.
    stageB2(0);
    stageB2(1);
    LOAD_A(afA, ap)
    const int8_t* apn = ap + 64;   // A slice 1 onward
    CKPTN(10)
    BAR()

    // s = 0..59 uniform: stage s+2, load A(s+1), CKPT(10)
    for (int s4 = 0; s4 < 15; ++s4) {
        int s = s4 * 4;
        SP(0, afA, afB, s + 2, 1, 1, 10)
        SP(1, afB, afA, s + 3, 1, 1, 10)
        SP(2, afA, afB, s + 4, 1, 1, 10)
        SP(3, afB, afA, s + 5, 1, 1, 10)
    }
    // tail: s = 60..63
    SP(0, afA, afB, 62, 1, 1, 10)   // s=60
    SP(1, afB, afA, 63, 1, 1, 10)   // s=61
    SP(2, afA, afB, 0,  0, 1, 8)    // s=62: no stage; CKPT(8) drains Bst63
    SP(3, afB, afA, 0,  0, 0, -1)   // s=63: MFMA only

    // epilogue: C/D layout col = lane&15, row = (lane>>4)*4 + reg.
    // out = sx[row]*sw[col]*acc + bias.
    int    colb = bn * 256 + wn * 64;
    size_t rowb = (size_t)bm * 256 + wm * 128 + (lk << 2);
    float sxv[8][4];
    #pragma unroll
    for (int f = 0; f < 8; ++f)
        #pragma unroll
        for (int rg = 0; rg < 4; ++rg)
            sxv[f][rg] = sx[rowb + f * 16 + rg];
    #pragma unroll
    for (int g = 0; g < 4; ++g) {
        int col = colb + g * 16 + l16;
        float scw = sw[col];
        float bv  = bias[col];
        #pragma unroll
        for (int f = 0; f < 8; ++f) {
            size_t r0 = rowb + f * 16;
            #pragma unroll
            for (int rg = 0; rg < 4; ++rg)
                C[(r0 + rg) * N_DIM + col] = (float)acc[f][g][rg] * (sxv[f][rg] * scw) + bv;
        }
    }
}

extern "C" void kernel_launch(void* const* d_in, const int* in_sizes, int n_in,
                              void* d_out, int out_size, void* d_ws, size_t ws_size,
                              hipStream_t stream) {
    const float* x    = (const float*)d_in[0];
    const float* W    = (const float*)d_in[1];
    const float* bias = (const float*)d_in[2];
    float* out = (float*)d_out;

    char* ws = (char*)d_ws;
    int8_t*   xq  = (int8_t*)ws;                                             // 32 MB
    int8_t*   wq  = (int8_t*)(ws + (size_t)M_DIM * K_DIM);                   // 16 MB
    uint16_t* sel = (uint16_t*)(ws + (size_t)M_DIM * K_DIM
                                   + (size_t)N_DIM * K_DIM);                 // 64 KB
    float*    sx  = (float*)((char*)sel + (size_t)(M_DIM / 64) * CBN * 2);   // 32 KB
    float*    sw  = (float*)((char*)sx + (size_t)M_DIM * 4);                 // 16 KB

    venom_sel  <<<dim3(64, 16), 256, 0, stream>>>(W, sel);
    venom_packq<<<dim3(N_DIM), 256, 0, stream>>>(W, sel, wq, sw);
    xq_kernel  <<<dim3(M_DIM), 256, 0, stream>>>(x, xq, sx);
    gemm256_i8 <<<dim3((M_DIM / 256) * (N_DIM / 256)), 512, 0, stream>>>(xq, wq, sx, sw, bias, out);
}

// Round 18
// 203.610 us; speedup vs baseline: 2.1167x; 2.1167x over previous
//
#include <hip/hip_runtime.h>
#include <stdint.h>

#define M_DIM 8192
#define N_DIM 4096
#define K_DIM 4096
#define CBN   (K_DIM/8)   // 512 column groups per row

typedef __attribute__((ext_vector_type(4)))  int   i32x4;
typedef __attribute__((ext_vector_type(16))) char  i8x16;

#define AS_GLOBAL(p) (const __attribute__((address_space(1))) void*)(p)
#define AS_LDS(p)    (__attribute__((address_space(3))) void*)(p)

// ---------------------------------------------------------------------------
// Kernel 1: per (ob, cb) pick top-4 columns (of 8) by L1 mass over 64 rows.
// ---------------------------------------------------------------------------
__global__ __launch_bounds__(256) void venom_sel(const float* __restrict__ W,
                                                 uint16_t* __restrict__ sel) {
    int t   = threadIdx.x;
    int ob  = blockIdx.x;
    int col = blockIdx.y * 256 + t;
    const float* p = W + (size_t)(ob * 64) * K_DIM + col;
    double s = 0.0;
    #pragma unroll 16
    for (int r = 0; r < 64; ++r) s += fabsf(p[(size_t)r * K_DIM]);

    int lane = t & 63;
    int base = lane & ~7;
    double sc[8];
    #pragma unroll
    for (int j = 0; j < 8; ++j) sc[j] = __shfl(s, base + j, 64);

    uint32_t packed = 0;
    #pragma unroll
    for (int c = 0; c < 8; ++c) {
        int rank = 0;
        #pragma unroll
        for (int j = 0; j < 8; ++j)
            rank += (sc[j] > sc[c]) || (sc[j] == sc[c] && j < c);
        if (rank < 4) packed |= (uint32_t)c << (4 * rank);
    }
    if ((lane & 7) == 0) {
        int cb = col >> 3;
        sel[ob * CBN + cb] = (uint16_t)packed;
    }
}

// ---------------------------------------------------------------------------
// Kernel 2: masked weight -> int8 with per-output-row symmetric scale.
// ---------------------------------------------------------------------------
__global__ __launch_bounds__(256) void venom_packq(const float* __restrict__ W,
                                                   const uint16_t* __restrict__ sel,
                                                   int8_t* __restrict__ Wq,
                                                   float* __restrict__ sw) {
    __shared__ float red[4];
    int o = blockIdx.x;
    const float* rowp = W + (size_t)o * K_DIM;
    float mv[16];
    float m = 0.0f;
    #pragma unroll
    for (int h = 0; h < 2; ++h) {
        int cb = threadIdx.x * 2 + h;
        uint32_t pk = sel[(o >> 6) * CBN + cb];
        const float* p = rowp + cb * 8;
        float4 a = *(const float4*)p;
        float4 b = *(const float4*)(p + 4);
        float w[8] = {a.x, a.y, a.z, a.w, b.x, b.y, b.z, b.w};
        int   c[4]; float v[4];
        #pragma unroll
        for (int pz = 0; pz < 4; ++pz) {
            c[pz] = (pk >> (4 * pz)) & 7;
            v[pz] = fabsf(w[c[pz]]);
        }
        uint32_t keep = 0;
        #pragma unroll
        for (int pz = 0; pz < 4; ++pz) {
            int cnt = 0;
            #pragma unroll
            for (int q = 0; q < 4; ++q)
                cnt += (v[q] > v[pz]) || (v[q] == v[pz] && q < pz);
            if (cnt < 2) keep |= 1u << c[pz];
        }
        #pragma unroll
        for (int j = 0; j < 8; ++j) {
            float x = ((keep >> j) & 1) ? w[j] : 0.0f;
            mv[h * 8 + j] = x;
            m = fmaxf(m, fabsf(x));
        }
    }
    #pragma unroll
    for (int off = 32; off >= 1; off >>= 1) m = fmaxf(m, __shfl_xor(m, off, 64));
    int lane = threadIdx.x & 63, wid = threadIdx.x >> 6;
    if (lane == 0) red[wid] = m;
    __syncthreads();
    m = fmaxf(fmaxf(red[0], red[1]), fmaxf(red[2], red[3]));
    float inv = m > 0.0f ? 127.0f / m : 0.0f;

    i8x16 q;
    #pragma unroll
    for (int j = 0; j < 16; ++j) {
        float qq = rintf(mv[j] * inv);
        qq = fminf(127.0f, fmaxf(-127.0f, qq));
        q[j] = (char)(int)qq;
    }
    *(i8x16*)(Wq + (size_t)o * K_DIM + threadIdx.x * 16) = q;
    if (threadIdx.x == 0) sw[o] = m > 0.0f ? m / 127.0f : 1.0f;
}

// ---------------------------------------------------------------------------
// Kernel 3: x f32 -> int8 with per-row symmetric scale. One block per row.
// ---------------------------------------------------------------------------
__global__ __launch_bounds__(256) void xq_kernel(const float* __restrict__ X,
                                                 int8_t* __restrict__ Xq,
                                                 float* __restrict__ sx) {
    __shared__ float red[4];
    int row = blockIdx.x;
    const float4* p = (const float4*)(X + (size_t)row * K_DIM) + threadIdx.x * 4;
    float4 v0 = p[0], v1 = p[1], v2 = p[2], v3 = p[3];
    float vv[16] = {v0.x, v0.y, v0.z, v0.w, v1.x, v1.y, v1.z, v1.w,
                    v2.x, v2.y, v2.z, v2.w, v3.x, v3.y, v3.z, v3.w};
    float m = 0.0f;
    #pragma unroll
    for (int j = 0; j < 16; ++j) m = fmaxf(m, fabsf(vv[j]));
    #pragma unroll
    for (int off = 32; off >= 1; off >>= 1) m = fmaxf(m, __shfl_xor(m, off, 64));
    int lane = threadIdx.x & 63, wid = threadIdx.x >> 6;
    if (lane == 0) red[wid] = m;
    __syncthreads();
    m = fmaxf(fmaxf(red[0], red[1]), fmaxf(red[2], red[3]));
    float inv = m > 0.0f ? 127.0f / m : 0.0f;

    i8x16 q;
    #pragma unroll
    for (int j = 0; j < 16; ++j) {
        float qq = rintf(vv[j] * inv);
        qq = fminf(127.0f, fmaxf(-127.0f, qq));
        q[j] = (char)(int)qq;
    }
    *(i8x16*)(Xq + (size_t)row * K_DIM + threadIdx.x * 16) = q;
    if (threadIdx.x == 0) sx[row] = m > 0.0f ? m / 127.0f : 1.0f;
}

// ---------------------------------------------------------------------------
// Kernel 4: 256x256 int8 GEMM, FULL REGISTER PREFETCH — no lgkm wait between
// read-issue and MFMA. Mechanism: LDS service is fair-RR across waves, so
// issue-order staggering can't desync waves (rounds 9-12 nulls); the only
// overlap path is frags prefetched ONE SLICE AHEAD so the MFMA cluster runs
// with zero pending lgkm, while the NEXT slice's 12 ds_reads (issued at SP
// top) are serviced under the 1306cy MFMA window. lgkm(0) moves to SP END
// (~free). Distinct from all prior variants: r3/7/13 waited lgkm before
// MFMA; r9 read after MFMA (LDS idle during MFMA); r5 kept lgkm(4-8) waits.
//   SP s: { RDNXT: 12 ds_read slice s+1 <- region (s+1)&1 | stage slice s+2
//           -> region s&1 (4 gload_lds) | sched_barrier | 32 MFMA (cur, NO
//           WAIT) | lgkm(0) | vmcnt(0) | BAR }
// Ledger (2 regions x (A 16KB + B 16KB), stage-lead 2):
//   R-after-W: reads@s (slice s+1) <- staged@s-1, drained CKPT0@s-1 + BAR.
//   W-after-R: stage@s overwrites region of slice s; slice s frags were read
//     @s-1, drained lgkm(0)@s-1 before BAR@s-1.
//   CKPT0@s also guarantees stage(s+2) complete before reads@s+1 (1 barrier).
//   Tail: s=62 no stage/no CKPT (stage@61 drained @61); s=63 no reads.
// Frag regs double-buffered with STATIC names (rule #20): afc/bfc, afn/bfn,
// 2-unrolled loop. VGPR ~ acc128 + frags 96 + addr ~= 240 <= 256 @ (512,2).
// Frags 16x16x64 i8; XOR 16B-chunk swizzle (0 conflicts); XCD block swizzle.
// ---------------------------------------------------------------------------
__global__ __launch_bounds__(512, 2) void gemm256_i8(const int8_t* __restrict__ A,
                                                     const int8_t* __restrict__ B,
                                                     const float* __restrict__ sx,
                                                     const float* __restrict__ sw,
                                                     const float* __restrict__ bias,
                                                     float* __restrict__ C) {
    __shared__ __align__(16) unsigned char smem[65536]; // A:2x16KB@0, B:2x16KB@32K

    int t    = threadIdx.x;
    int wid  = t >> 6;
    int lane = t & 63;
    int l16  = lane & 15;
    int lk   = lane >> 4;
    int wm   = wid >> 2;     // wave row-half (128 rows)
    int wn   = wid & 3;      // wave col-quarter (64 cols)

    // XCD-aware bijective swizzle (512 blocks % 8 == 0)
    int bid = blockIdx.x;
    int swz = (bid & 7) * ((int)gridDim.x >> 3) + (bid >> 3);
    int bm  = swz >> 4;
    int bn  = swz & 15;

    // staging: thread t covers row r=t>>2 (and r+128); stored 16B chunk t&3
    // holds logical chunk (t&3)^((r>>1)&3) = (t&3)^((t>>3)&3)
    int gch = ((t & 3) ^ ((t >> 3) & 3)) * 16;
    const int8_t* agbase = A + (size_t)(bm * 256 + (t >> 2)) * K_DIM + gch;
    const int8_t* bgbase = B + (size_t)(bn * 256 + (t >> 2)) * K_DIM + gch;

    auto stageAB = [&](int slice) {
        const int8_t* ga = agbase + slice * 64;
        const int8_t* gb = bgbase + slice * 64;
        char* la = (char*)smem + (slice & 1) * 16384 + wid * 1024;
        char* lb = la + 32768;
        __builtin_amdgcn_global_load_lds(AS_GLOBAL(ga), AS_LDS(la), 16, 0, 0);
        __builtin_amdgcn_global_load_lds(AS_GLOBAL(ga + (size_t)128 * K_DIM), AS_LDS(la + 8192), 16, 0, 0);
        __builtin_amdgcn_global_load_lds(AS_GLOBAL(gb), AS_LDS(lb), 16, 0, 0);
        __builtin_amdgcn_global_load_lds(AS_GLOBAL(gb + (size_t)128 * K_DIM), AS_LDS(lb + 8192), 16, 0, 0);
    };

    // read-side: row R = base+l16, 16B chunk lk -> phys chunk lk^((l16>>1)&3)
    int koff = ((lk ^ ((l16 >> 1) & 3)) << 4);
    const char* ardb = (const char*)smem + (wm * 128 + l16) * 64 + koff;
    const char* brdb = (const char*)smem + 32768 + (wn * 64 + l16) * 64 + koff;

    i32x4 acc[8][4] = {};
    i32x4 afc[8], bfc[4], afn[8], bfn[4];

#define LGKM0() { asm volatile("s_waitcnt lgkmcnt(0)" ::: "memory");                 \
                  __builtin_amdgcn_sched_barrier(0); }
#define CKPT0() { asm volatile("s_waitcnt vmcnt(0)" ::: "memory");                   \
                  __builtin_amdgcn_sched_barrier(0); }
#define BAR()   { __builtin_amdgcn_s_barrier(); __builtin_amdgcn_sched_barrier(0); }
#define SB()    { __builtin_amdgcn_sched_barrier(0); }

#define RDTO(AF, BF, RN)                                                             \
    {                                                                                \
        _Pragma("unroll")                                                            \
        for (int g = 0; g < 4; ++g)                                                  \
            BF[g] = *(const i32x4*)(brdb + (RN) * 16384 + g * 1024);                 \
        _Pragma("unroll")                                                            \
        for (int i = 0; i < 8; ++i)                                                  \
            AF[i] = *(const i32x4*)(ardb + (RN) * 16384 + i * 1024);                 \
    }

#define MFMA32(AF, BF)                                                               \
    {                                                                                \
        __builtin_amdgcn_s_setprio(1);                                               \
        _Pragma("unroll")                                                            \
        for (int i = 0; i < 8; ++i)                                                  \
            _Pragma("unroll")                                                        \
            for (int g = 0; g < 4; ++g)                                              \
                acc[i][g] = __builtin_amdgcn_mfma_i32_16x16x64_i8(AF[i], BF[g], acc[i][g], 0, 0, 0); \
        __builtin_amdgcn_s_setprio(0);                                               \
        __builtin_amdgcn_sched_barrier(0);                                           \
    }

    // SP: CUR frags consumed; NXT frags loaded from region (s+1)&1.
    // DORD: load next; DOSTAGE+SS: stage slice s+2; DOCK: CKPT0.
#define SP(AFC, BFC, AFN, BFN, RNN, DORD, DOSTAGE, SS, DOCK)                         \
    {                                                                                \
        if (DORD) RDTO(AFN, BFN, RNN)                                                \
        if (DOSTAGE) stageAB(SS);                                                    \
        SB()                                                                         \
        MFMA32(AFC, BFC)                                                             \
        if (DORD) LGKM0()                                                            \
        if (DOCK) { CKPT0() }                                                        \
        BAR()                                                                        \
    }

    // prologue: stage slices 0,1; drain; sync; prefetch slice 0 into cur.
    stageAB(0);
    stageAB(1);
    CKPT0()
    BAR()
    RDTO(afc, bfc, 0)
    LGKM0()

    // 64 slices; 2-unrolled for static cur/nxt swap. stage s+2 for s<=61.
    for (int s2 = 0; s2 < 31; ++s2) {
        int s = s2 * 2;
        SP(afc, bfc, afn, bfn, 1, 1, 1, s + 2, 1)   // even s: cur=afc
        SP(afn, bfn, afc, bfc, 0, 1, 1, s + 3, 1)   // odd  s: cur=afn
    }
    SP(afc, bfc, afn, bfn, 1, 1, 0, 0, 0)           // s=62: no stage/CKPT
    SP(afn, bfn, afc, bfc, 0, 0, 0, 0, 0)           // s=63: MFMA only

    // epilogue: C/D layout col = lane&15, row = (lane>>4)*4 + reg.
    // out = sx[row]*sw[col]*acc + bias.
    int    colb = bn * 256 + wn * 64;
    size_t rowb = (size_t)bm * 256 + wm * 128 + (lk << 2);
    float sxv[8][4];
    #pragma unroll
    for (int f = 0; f < 8; ++f)
        #pragma unroll
        for (int rg = 0; rg < 4; ++rg)
            sxv[f][rg] = sx[rowb + f * 16 + rg];
    #pragma unroll
    for (int g = 0; g < 4; ++g) {
        int col = colb + g * 16 + l16;
        float scw = sw[col];
        float bv  = bias[col];
        #pragma unroll
        for (int f = 0; f < 8; ++f) {
            size_t r0 = rowb + f * 16;
            #pragma unroll
            for (int rg = 0; rg < 4; ++rg)
                C[(r0 + rg) * N_DIM + col] = (float)acc[f][g][rg] * (sxv[f][rg] * scw) + bv;
        }
    }
}

extern "C" void kernel_launch(void* const* d_in, const int* in_sizes, int n_in,
                              void* d_out, int out_size, void* d_ws, size_t ws_size,
                              hipStream_t stream) {
    const float* x    = (const float*)d_in[0];
    const float* W    = (const float*)d_in[1];
    const float* bias = (const float*)d_in[2];
    float* out = (float*)d_out;

    char* ws = (char*)d_ws;
    int8_t*   xq  = (int8_t*)ws;                                             // 32 MB
    int8_t*   wq  = (int8_t*)(ws + (size_t)M_DIM * K_DIM);                   // 16 MB
    uint16_t* sel = (uint16_t*)(ws + (size_t)M_DIM * K_DIM
                                   + (size_t)N_DIM * K_DIM);                 // 64 KB
    float*    sx  = (float*)((char*)sel + (size_t)(M_DIM / 64) * CBN * 2);   // 32 KB
    float*    sw  = (float*)((char*)sx + (size_t)M_DIM * 4);                 // 16 KB

    venom_sel  <<<dim3(64, 16), 256, 0, stream>>>(W, sel);
    venom_packq<<<dim3(N_DIM), 256, 0, stream>>>(W, sel, wq, sw);
    xq_kernel  <<<dim3(M_DIM), 256, 0, stream>>>(x, xq, sx);
    gemm256_i8 <<<dim3((M_DIM / 256) * (N_DIM / 256)), 512, 0, stream>>>(xq, wq, sx, sw, bias, out);
}